// Round 5
// baseline (6672.662 us; speedup 1.0000x reference)
//
#include <hip/hip_runtime.h>
#include <hip/hip_bf16.h>
#include <stdint.h>

// Problem constants
#define HD    256      // hidden
#define LL    50       // friend seq len
#define SS    50       // common seq len
#define NB    64       // batch
#define MAXF  32
#define NSEQ  2048     // NB*MAXF
#define MB    32       // sequences per block (one 32-row MFMA M-tile)
#define NBLK  64       // NSEQ/MB
#define XP    264      // padded LDS row (bf16 elems): 528B rows (0 conflicts measured R4)

typedef __attribute__((ext_vector_type(8)))  short bf16x8;
typedef __attribute__((ext_vector_type(16))) float f32x16;
typedef __attribute__((ext_vector_type(4)))  float f32x4v;
typedef __attribute__((ext_vector_type(4)))  unsigned short u16x4;

__device__ __forceinline__ f32x16 mfma32(bf16x8 a, bf16x8 b, f32x16 c) {
    return __builtin_amdgcn_mfma_f32_32x32x16_bf16(a, b, c, 0, 0, 0);
}

__device__ __forceinline__ unsigned short f2bf_rne(float f) {
    union { float f; uint32_t u; } v; v.f = f;
    uint32_t u = v.u;
    uint32_t r = u + 0x7FFFu + ((u >> 16) & 1u);
    return (unsigned short)(r >> 16);
}
__device__ __forceinline__ float bf2f(unsigned short b) {
    union { float f; uint32_t u; } v; v.u = ((uint32_t)b) << 16;
    return v.f;
}

// ---------------------------------------------------------------------------
// Pack weights -> per-wave(8) MFMA 32x32x16 fragment stream + Wf^T.
// wpk idx = ((((((wv*2+l)*2+m)*16+ks)*3+gate)*2+plane)*64+lane)*8+j
//   W row n = gate*256 + wv*32 + (lane&31);  k = ks*16 + (lane>>5)*8 + j
// Per (l,m,ks) group for a wave: 6 contiguous 1KB fragments (6144 B).
// ---------------------------------------------------------------------------
__global__ void pack_kernel(const float* __restrict__ Wih0, const float* __restrict__ Whh0,
                            const float* __restrict__ Wih1, const float* __restrict__ Whh1,
                            const float* __restrict__ Wf,
                            unsigned short* __restrict__ wpk,
                            float* __restrict__ WfT) {
    int idx = blockIdx.x * blockDim.x + threadIdx.x;
    const int TOTW = 1572864;
    if (idx < TOTW) {
        int j     = idx & 7;
        int lane  = (idx >> 3) & 63;
        int plane = (idx >> 9) & 1;
        int gate  = (idx >> 10) % 3;
        int rest  = (idx >> 10) / 3;         // ((wv*2+l)*2+m)*16 + ks
        int ks    = rest & 15;
        int m     = (rest >> 4) & 1;
        int l     = (rest >> 5) & 1;
        int wvv   = rest >> 6;
        const float* W = (l == 0) ? (m == 0 ? Wih0 : Whh0)
                                  : (m == 0 ? Wih1 : Whh1);
        int n = gate * 256 + wvv * 32 + (lane & 31);
        int k = ks * 16 + (lane >> 5) * 8 + j;
        float v = W[n * HD + k];
        unsigned short hi = f2bf_rne(v);
        wpk[idx] = plane ? f2bf_rne(v - bf2f(hi)) : hi;
    } else {
        int idx2 = idx - TOTW;
        if (idx2 < 512 * 256) {              // WfT[k][h] = Wf[h][k]
            int k = idx2 >> 8; int h = idx2 & 255;
            WfT[k * 256 + h] = Wf[h * 512 + k];
        }
    }
}

// ---------------------------------------------------------------------------
// Counting sort of the 2048 sequences by friend_len (1..50), ascending.
// ---------------------------------------------------------------------------
__global__ void sort_kernel(const int* __restrict__ flen, int* __restrict__ sid) {
    __shared__ int hist[64];
    __shared__ int offs[64];
    int tid = threadIdx.x;
    if (tid < 64) hist[tid] = 0;
    __syncthreads();
    for (int i = tid; i < NSEQ; i += blockDim.x) atomicAdd(&hist[flen[i]], 1);
    __syncthreads();
    if (tid == 0) {
        int acc = 0;
        for (int v = 1; v <= 50; v++) { offs[v] = acc; acc += hist[v]; }
    }
    __syncthreads();
    for (int i = tid; i < NSEQ; i += blockDim.x) {
        int pos = atomicAdd(&offs[flen[i]], 1);
        sid[pos] = i;
    }
}

// ---------------------------------------------------------------------------
// Fused 2-layer GRU. 512 threads = 8 waves = 2 waves/SIMD (latency hiding).
// Wave w owns gate columns [32w, 32w+32) of r/z/n. mfma_f32_32x32x16_bf16,
// split-bf16 (hi+lo) 3-term. Depth-2 weight-group prefetch; X double-buffered
// in LDS with staging hidden under layer-1 compute. nt loads/stores for the
// streaming friend_x / friend_last to keep the 3MB weight set L2-resident.
// ---------------------------------------------------------------------------
__global__ __launch_bounds__(512) __attribute__((amdgpu_waves_per_eu(2, 2)))
void gru_kernel(const float* __restrict__ friend_x,
                const int* __restrict__ flen,
                const int* __restrict__ sid,
                const unsigned short* __restrict__ wpk,
                const float* __restrict__ bih0, const float* __restrict__ bhh0,
                const float* __restrict__ bih1, const float* __restrict__ bhh1,
                float* __restrict__ friend_last) {
    __shared__ __align__(16) unsigned short Xhi[2][MB][XP], Xlo[2][MB][XP];
    __shared__ __align__(16) unsigned short H0hi[MB][XP],   H0lo[MB][XP];
    __shared__ __align__(16) unsigned short H1hi[MB][XP],   H1lo[MB][XP];
    __shared__ int sidS[MB], lenS[MB];

    const int tid  = threadIdx.x;
    const int g    = blockIdx.x;
    const int wv   = tid >> 6;          // 0..7
    const int lane = tid & 63;
    const int l31  = lane & 31;
    const int half = lane >> 5;

    if (tid < MB) {
        int s_ = sid[g * MB + tid];
        sidS[tid] = s_;
        lenS[tid] = flen[s_];
    }
    for (int i = tid; i < MB * XP / 2; i += 512) {
        ((uint32_t*)&H0hi[0][0])[i] = 0; ((uint32_t*)&H0lo[0][0])[i] = 0;
        ((uint32_t*)&H1hi[0][0])[i] = 0; ((uint32_t*)&H1lo[0][0])[i] = 0;
    }
    __syncthreads();

    int maxlen = 0;
#pragma unroll
    for (int s = 0; s < MB; s++) maxlen = max(maxlen, lenS[s]);

    const int j = wv * 32 + l31;        // this lane's gate column

    const float b0R  = bih0[j] + bhh0[j];
    const float b0Z  = bih0[256 + j] + bhh0[256 + j];
    const float b0Ni = bih0[512 + j];
    const float b0Nh = bhh0[512 + j];
    const float b1R  = bih1[j] + bhh1[j];
    const float b1Z  = bih1[256 + j] + bhh1[256 + j];
    const float b1Ni = bih1[512 + j];
    const float b1Nh = bhh1[512 + j];

    int srow[4];                        // this wave stages rows wv*4 .. wv*4+3
#pragma unroll
    for (int r = 0; r < 4; r++) srow[r] = sidS[wv * 4 + r];

    float h0c[16], h1c[16];             // fp32 hidden carry (C-layout regs)
#pragma unroll
    for (int rg = 0; rg < 16; rg++) { h0c[rg] = 0.f; h1c[rg] = 0.f; }

    const int fragBase = l31 * XP + half * 8;
    const unsigned short* wbase = wpk + (size_t)wv * 196608 + (size_t)lane * 8;

    // ---- staging helpers (x(t) -> X[buf], wave-private rows) ----
    auto stageLoad = [&](int tsrc, f32x4v* sx) {
#pragma unroll
        for (int r = 0; r < 4; r++)
            sx[r] = __builtin_nontemporal_load(
                (const f32x4v*)(friend_x + ((size_t)srow[r] * LL + tsrc) * HD) + lane);
    };
    auto stageWrite = [&](int buf, const f32x4v* sx) {
#pragma unroll
        for (int r = 0; r < 4; r++) {
            int row = wv * 4 + r;
            u16x4 hi4, lo4;
#pragma unroll
            for (int e = 0; e < 4; e++) {
                unsigned short h_ = f2bf_rne(sx[r][e]);
                hi4[e] = h_;
                lo4[e] = f2bf_rne(sx[r][e] - bf2f(h_));
            }
            *(u16x4*)&Xhi[buf][row][lane * 4] = hi4;
            *(u16x4*)&Xlo[buf][row][lane * 4] = lo4;
        }
    };

    // ---- one layer's MFMA phase: 32 weight-groups, depth-2 prefetch ----
    auto layerMM = [&](const unsigned short* pL,
                       const unsigned short* A0h, const unsigned short* A0l,
                       const unsigned short* A1h, const unsigned short* A1l,
                       f32x16& aR, f32x16& aZ, f32x16& aNi, f32x16& aNh) {
        bf16x8 B[3][6], ahb[3], alb[3];
        auto pf = [&](int buf, int grp) {
            const unsigned short* p = pL + (size_t)grp * 3072;
#pragma unroll
            for (int f = 0; f < 6; f++) B[buf][f] = *(const bf16x8*)(p + f * 512);
            const unsigned short* Ah = (grp < 16) ? A0h : A1h;
            const unsigned short* Al = (grp < 16) ? A0l : A1l;
            int off = fragBase + (grp & 15) * 16;
            ahb[buf] = *(const bf16x8*)(Ah + off);
            alb[buf] = *(const bf16x8*)(Al + off);
        };
        pf(0, 0); pf(1, 1);
#pragma unroll
        for (int grp = 0; grp < 32; grp++) {
            const int cur = grp % 3;
            if (grp + 2 < 32) pf((grp + 2) % 3, grp + 2);
            f32x16& aN = (grp < 16) ? aNi : aNh;
            const bf16x8 ah = ahb[cur], al = alb[cur];
            aR = mfma32(ah, B[cur][0], aR);
            aR = mfma32(al, B[cur][0], aR);
            aR = mfma32(ah, B[cur][1], aR);
            aZ = mfma32(ah, B[cur][2], aZ);
            aZ = mfma32(al, B[cur][2], aZ);
            aZ = mfma32(ah, B[cur][3], aZ);
            aN = mfma32(ah, B[cur][4], aN);
            aN = mfma32(al, B[cur][4], aN);
            aN = mfma32(ah, B[cur][5], aN);
        }
    };

    auto initAcc = [&](f32x16& a, float b) {
#pragma unroll
        for (int i = 0; i < 16; i++) a[i] = b;
    };

    // gate epilogue; C-layout: col = lane&31, row = (rg&3)+8*(rg>>2)+4*half
    auto epi = [&](f32x16& aR, f32x16& aZ, f32x16& aNi, f32x16& aNh, float* hc,
                   unsigned short (*Ohi)[XP], unsigned short (*Olo)[XP],
                   bool gather, int t) {
#pragma unroll
        for (int rg = 0; rg < 16; rg++) {
            const int row = (rg & 3) + ((rg >> 2) << 3) + (half << 2);
            float rr = 1.f / (1.f + __expf(-aR[rg]));
            float zz = 1.f / (1.f + __expf(-aZ[rg]));
            float nx = aNi[rg] + rr * aNh[rg];
            float e  = __expf(-2.f * fabsf(nx));
            float th = 1.f - 2.f * e / (1.f + e);
            th = (nx < 0.f) ? -th : th;
            float hNew = (1.f - zz) * th + zz * hc[rg];
            hc[rg] = hNew;
            unsigned short hi_ = f2bf_rne(hNew);
            Ohi[row][j] = hi_;
            Olo[row][j] = f2bf_rne(hNew - bf2f(hi_));
            if (gather && t == lenS[row] - 1)
                __builtin_nontemporal_store(hNew, friend_last + (size_t)sidS[row] * HD + j);
        }
    };

    // stage x(0) into X[0]
    {
        f32x4v sx[4];
        stageLoad(0, sx);
        stageWrite(0, sx);
    }
    __syncthreads();

#pragma unroll 1
    for (int t = 0; t < maxlen; t++) {
        const int cb = t & 1, nb = cb ^ 1;
        // ---- Layer 0: A0 = x(t) [X[cb]], A1 = h0(t-1) ----
        f32x16 aR, aZ, aNi, aNh;
        initAcc(aR, b0R); initAcc(aZ, b0Z); initAcc(aNi, b0Ni); initAcc(aNh, b0Nh);
        layerMM(wbase, &Xhi[cb][0][0], &Xlo[cb][0][0], &H0hi[0][0], &H0lo[0][0],
                aR, aZ, aNi, aNh);
        __syncthreads();               // B1: X/H0 reads complete
        epi(aR, aZ, aNi, aNh, h0c, H0hi, H0lo, false, t);
        __syncthreads();               // B2: h0(t) visible
        // ---- Layer 1: A0 = h0(t), A1 = h1(t-1); staging hidden underneath ----
        int tn = (t + 1 < maxlen) ? t + 1 : t;
        f32x4v sx[4];
        stageLoad(tn, sx);             // in flight during layer-1 MFMAs
        initAcc(aR, b1R); initAcc(aZ, b1Z); initAcc(aNi, b1Ni); initAcc(aNh, b1Nh);
        layerMM(wbase + 98304, &H0hi[0][0], &H0lo[0][0], &H1hi[0][0], &H1lo[0][0],
                aR, aZ, aNi, aNh);
        stageWrite(nb, sx);            // x(t+1) -> X[nb] (wave-private rows)
        __syncthreads();               // B3: H0/H1 reads + X[nb] writes complete
        epi(aR, aZ, aNi, aNh, h1c, H1hi, H1lo, true, t);
        // epi(l1) writes H1; next-step readers of H1 are after next B2
    }
}

// ---------------------------------------------------------------------------
// Fused: sf[n,h] = Wf[h,:256]·self_x[b] + Wf[h,256:]·fl[n]; v[n,h] = Wb[:,h]·sf[n,:]
// ---------------------------------------------------------------------------
__global__ __launch_bounds__(256)
void sfv_kernel(const float* __restrict__ self_x, const float* __restrict__ fl,
                const float* __restrict__ WfT, const float* __restrict__ Wb,
                float* __restrict__ vout) {
    __shared__ float S[256];
    __shared__ float T[256][33];   // phase1: fl^T [k][f]; phase2: sf^T [g][f]
    int b = blockIdx.x, tid = threadIdx.x;
    S[tid] = self_x[b * 256 + tid];
    for (int i = tid; i < 32 * 256; i += 256) {
        int f = i >> 8, k = i & 255;
        T[k][f] = fl[((size_t)(b * 32 + f)) * 256 + k];
    }
    __syncthreads();
    float acc0 = 0.f;
    for (int k = 0; k < 256; k++) acc0 += WfT[k * 256 + tid] * S[k];
    float acc[32];
#pragma unroll
    for (int f = 0; f < 32; f++) acc[f] = acc0;
    for (int k = 0; k < 256; k++) {
        float w = WfT[(256 + k) * 256 + tid];
#pragma unroll
        for (int f = 0; f < 32; f++) acc[f] += w * T[k][f];
    }
    __syncthreads();
#pragma unroll
    for (int f = 0; f < 32; f++) T[tid][f] = acc[f];   // sf^T into LDS
    __syncthreads();
    float av[32];
#pragma unroll
    for (int f = 0; f < 32; f++) av[f] = 0.f;
    for (int gg = 0; gg < 256; gg++) {
        float w = Wb[gg * 256 + tid];
#pragma unroll
        for (int f = 0; f < 32; f++) av[f] += w * T[gg][f];
    }
#pragma unroll
    for (int f = 0; f < 32; f++)
        vout[((size_t)(b * 32 + f)) * 256 + tid] = av[f];
}

// ---------------------------------------------------------------------------
// tf[n] = sum_s softplus(common_x[n,s,:]·v[n,:]) * exp(-time) * (s < clen)
// ---------------------------------------------------------------------------
__global__ __launch_bounds__(256)
void tf_kernel(const float* __restrict__ common_x, const float* __restrict__ common_time,
               const int* __restrict__ clen, const float* __restrict__ v,
               float* __restrict__ tf) {
    __shared__ float V[256];
    __shared__ float partial[4];
    int n = blockIdx.x, tid = threadIdx.x, wv = tid >> 6, lane = tid & 63;
    V[tid] = v[(size_t)n * 256 + tid];
    __syncthreads();
    float4 vv = ((const float4*)V)[lane];
    int cl = clen[n];
    float acc = 0.f;
    for (int s = wv; s < SS; s += 4) {
        float4 cx = ((const float4*)(common_x + ((size_t)n * SS + s) * HD))[lane];
        float d = cx.x * vv.x + cx.y * vv.y + cx.z * vv.z + cx.w * vv.w;
#pragma unroll
        for (int off = 32; off; off >>= 1) d += __shfl_xor(d, off);
        if (lane == 0 && s < cl) {
            float sp = (d > 20.f) ? d : log1pf(__expf(d));
            acc += sp * __expf(-common_time[n * SS + s]);
        }
    }
    if (lane == 0) partial[wv] = acc;
    __syncthreads();
    if (tid == 0) tf[n] = partial[0] + partial[1] + partial[2] + partial[3];
}

// ---------------------------------------------------------------------------
// softmax over padded MAXF (invalid logits exactly 0) + weighted sum.
// ---------------------------------------------------------------------------
__global__ __launch_bounds__(256)
void out_kernel(const float* __restrict__ tf, const int* __restrict__ fnum,
                const float* __restrict__ fl, float* __restrict__ out) {
    __shared__ float e[32];
    __shared__ float tfm[32];
    __shared__ float Zs;
    int b = blockIdx.x, tid = threadIdx.x;
    int nv = fnum[b];
    if (tid < 32) tfm[tid] = (tid < nv) ? tf[b * 32 + tid] : 0.f;
    __syncthreads();
    if (tid == 0) {
        float m = tfm[0];
        for (int f = 1; f < 32; f++) m = fmaxf(m, tfm[f]);
        float Z = 0.f;
        for (int f = 0; f < 32; f++) { e[f] = __expf(tfm[f] - m); Z += e[f]; }
        Zs = Z;
    }
    __syncthreads();
    float Zi = 1.f / Zs;
    float o = 0.f;
    for (int f = 0; f < nv; f++)
        o += e[f] * Zi * fl[((size_t)(b * 32 + f)) * 256 + tid];
    out[b * 256 + tid] = o;
}

// ---------------------------------------------------------------------------
extern "C" void kernel_launch(void* const* d_in, const int* in_sizes, int n_in,
                              void* d_out, int out_size, void* d_ws, size_t ws_size,
                              hipStream_t stream) {
    (void)in_sizes; (void)n_in; (void)out_size; (void)ws_size;
    const float* self_x      = (const float*)d_in[0];
    const float* common_x    = (const float*)d_in[1];
    const float* common_time = (const float*)d_in[2];
    const float* friend_x    = (const float*)d_in[3];
    const float* Wih0 = (const float*)d_in[4];
    const float* Whh0 = (const float*)d_in[5];
    const float* bih0 = (const float*)d_in[6];
    const float* bhh0 = (const float*)d_in[7];
    const float* Wih1 = (const float*)d_in[8];
    const float* Whh1 = (const float*)d_in[9];
    const float* bih1 = (const float*)d_in[10];
    const float* bhh1 = (const float*)d_in[11];
    const float* Wf   = (const float*)d_in[12];
    const float* Wb   = (const float*)d_in[13];
    const int* flen   = (const int*)d_in[14];
    const int* fnum   = (const int*)d_in[15];
    const int* clen   = (const int*)d_in[16];
    float* out = (float*)d_out;

    char* ws = (char*)d_ws;
    unsigned short* wpk = (unsigned short*)ws; ws += (size_t)1572864 * 2;
    float* WfT = (float*)ws;  ws += (size_t)512 * 256 * 4;
    int*   sid = (int*)ws;    ws += (size_t)2048 * 4;
    float* fl  = (float*)ws;  ws += (size_t)2048 * 256 * 4;
    float* vv  = (float*)ws;  ws += (size_t)2048 * 256 * 4;
    float* tf  = (float*)ws;  ws += (size_t)2048 * 4;

    pack_kernel<<<6656, 256, 0, stream>>>(Wih0, Whh0, Wih1, Whh1, Wf, wpk, WfT);
    sort_kernel<<<1, 256, 0, stream>>>(flen, sid);
    gru_kernel<<<NBLK, 512, 0, stream>>>(friend_x, flen, sid, wpk,
                                         bih0, bhh0, bih1, bhh1, fl);
    sfv_kernel<<<64, 256, 0, stream>>>(self_x, fl, WfT, Wb, vv);
    tf_kernel<<<2048, 256, 0, stream>>>(common_x, common_time, clen, vv, tf);
    out_kernel<<<64, 256, 0, stream>>>(tf, fnum, fl, out);
}